// Round 5
// baseline (1705.628 us; speedup 1.0000x reference)
//
#include <hip/hip_runtime.h>
#include <math.h>

// Problem constants
constexpr int NN    = 50000;
constexpr int NE    = 400000;
constexpr int HID   = 128;

// Workspace layout (float offsets)
// vecp1: [N][3][128] f32 (vec1 only — vec2 moved to bundle)  19.2M floats
// bun:   [N][1024] bf16 {vec2 | vec3 | hw_row | hw_col}      25.6M floats (51.2M shorts)
// hagg:  [N][128] f32                                          6.4M floats
constexpr size_t OFF_VECP1 = 0;
constexpr size_t OFF_BUN  = 19200000;
constexpr size_t OFF_HAGG = 44800000;
constexpr size_t OFF_WT   = 83200000;     // weights, 442368 shorts
constexpr size_t OFF_PERM = 83421184;     // int[400000]
constexpr size_t OFF_DEG  = 83821184;     // int[50000]
constexpr size_t OFF_CUR  = 83871184;     // int[50000]
constexpr size_t WS_FLOATS = 83921184;    // ~335.7 MB

// split-bf16 weight offsets (shorts, within wt region) — weights stay split
constexpr size_t O_HWH = 0;        // [256n][128k]
constexpr size_t O_HWL = 32768;
constexpr size_t O_W1H = 65536;    // [128n][192k]
constexpr size_t O_W1L = 90112;
constexpr size_t O_W2H = 114688;   // [128n][128k]
constexpr size_t O_W2L = 131072;
constexpr size_t O_W3H = 147456;   // [384n][128k]
constexpr size_t O_W3L = 196608;
constexpr size_t O_VPH = 245760;   // [384n][128k]
constexpr size_t O_VPL = 294912;
constexpr size_t O_OPH = 344064;   // [384n][128k]
constexpr size_t O_OPL = 393216;

typedef __attribute__((ext_vector_type(8))) short short8;
typedef __attribute__((ext_vector_type(4))) float f32x4;

__device__ __forceinline__ short f2bf_rne(float f) {
    unsigned u = __float_as_uint(f);
    u += 0x7fffu + ((u >> 16) & 1u);
    return (short)(u >> 16);
}
__device__ __forceinline__ float bf2f(short h) {
    return __uint_as_float(((unsigned)(unsigned short)h) << 16);
}
__device__ __forceinline__ short8 tobf8(const float* t) {
    short8 r;
#pragma unroll
    for (int j = 0; j < 8; ++j) r[j] = f2bf_rne(t[j]);
    return r;
}
// 2-term product: A single bf16 (activations already carry bf16-grade noise
// from the bundle; headroom 0.5 vs 3.06), weights split bf16 (bh+bl).
__device__ __forceinline__ f32x4 mfma2(short8 a, short8 bh, short8 bl, f32x4 c) {
    c = __builtin_amdgcn_mfma_f32_16x16x32_bf16(a, bh, c, 0, 0, 0);
    c = __builtin_amdgcn_mfma_f32_16x16x32_bf16(a, bl, c, 0, 0, 0);
    return c;
}

#define VLOAD8(dst, src) do { \
    *(float4*)&(dst)[0] = *(const float4*)(src); \
    *(float4*)&(dst)[4] = *(const float4*)((src) + 4); } while (0)

// ---------------------------------------------------------------------------
// misc: zero hagg/dvec (grid 25000) + wprep (blocks <864) + sort hist (<1563)
// ---------------------------------------------------------------------------
__global__ void misc_kernel(const float* __restrict__ W1, const float* __restrict__ W2,
                            const float* __restrict__ W3, const float* __restrict__ Wvp,
                            const float* __restrict__ Wop, short* __restrict__ wt,
                            const int* __restrict__ eidx, int* __restrict__ deg,
                            float* __restrict__ hagg, float* __restrict__ dvec)
{
    const int bid = blockIdx.x;
    const int idx = bid * 256 + threadIdx.x;
    {
        int n = idx >> 7, k = idx & 127;
        hagg[idx] = 0.f;
        size_t db = (size_t)n * 384 + k;
        dvec[db] = 0.f; dvec[db + 128] = 0.f; dvec[db + 256] = 0.f;
    }
    if (bid < 864) {   // weight split/transpose, idx < 221184
        float v; size_t oh, ol;
        if (idx < 32768) {
            int j = idx >> 7, k = idx & 127;
            v = (j < 128) ? W1[(size_t)k * 128 + j] : W1[(size_t)(128 + k) * 128 + (j - 128)];
            oh = O_HWH + idx; ol = O_HWL + idx;
        } else if (idx < 57344) {
            int l = idx - 32768; int n = l / 192, k = l - n * 192;
            int r = (k < 128) ? (288 + k) : (k < 160) ? (256 + k - 128) : (k < 176) ? (416 + k - 160) : -1;
            v = (r < 0) ? 0.f : W1[(size_t)r * 128 + n];
            oh = O_W1H + l; ol = O_W1L + l;
        } else if (idx < 73728) {
            int l = idx - 57344; int n = l >> 7, k = l & 127;
            v = W2[(size_t)k * 128 + n];
            oh = O_W2H + l; ol = O_W2L + l;
        } else if (idx < 122880) {
            int l = idx - 73728; int n = l >> 7, k = l & 127;
            v = W3[(size_t)k * 384 + n];
            oh = O_W3H + l; ol = O_W3L + l;
        } else if (idx < 172032) {
            int l = idx - 122880; int n = l >> 7, k = l & 127;
            v = Wvp[(size_t)k * 384 + n];
            oh = O_VPH + l; ol = O_VPL + l;
        } else {
            int l = idx - 172032; int n = l >> 7, k = l & 127;
            v = Wop[(size_t)k * 384 + n];
            oh = O_OPH + l; ol = O_OPL + l;
        }
        short hi = f2bf_rne(v);
        wt[oh] = hi;
        wt[ol] = f2bf_rne(v - bf2f(hi));
    }
    if (bid < 1563 && idx < NE)   // degree histogram
        atomicAdd(&deg[eidx[idx]], 1);
}

__global__ void __launch_bounds__(1024)
sort_scan(const int* __restrict__ deg, int* __restrict__ cursor)
{
    __shared__ int part[1024];
    const int tid = threadIdx.x;
    const int base = tid * 49;
    int s = 0;
#pragma unroll 7
    for (int j = 0; j < 49; ++j) {
        int i = base + j;
        if (i < NN) s += deg[i];
    }
    part[tid] = s;
    __syncthreads();
    for (int off = 1; off < 1024; off <<= 1) {
        int v = (tid >= off) ? part[tid - off] : 0;
        __syncthreads();
        part[tid] += v;
        __syncthreads();
    }
    int run = part[tid] - s;
    for (int j = 0; j < 49; ++j) {
        int i = base + j;
        if (i < NN) { cursor[i] = run; run += deg[i]; }
    }
}

__global__ void sort_scatter(const int* __restrict__ eidx, int* __restrict__ cursor,
                             int* __restrict__ perm)
{
    int e = blockIdx.x * 256 + threadIdx.x;
    if (e < NE) {
        int pos = atomicAdd(&cursor[eidx[e]], 1);
        perm[pos] = e;
    }
}

// ---------------------------------------------------------------------------
// vp-GEMM: [150000,128] @ Wvp^T -> vec1 f32 (vecp1) + vec2/vec3 bf16 (bundle)
// ---------------------------------------------------------------------------
__global__ void __launch_bounds__(256, 3)
gemm_vp(const float* __restrict__ A, int M,
        const short* __restrict__ wh, const short* __restrict__ wl,
        float* __restrict__ vecp1, short* __restrict__ bun)
{
    const int tid = threadIdx.x, wave = tid >> 6, lane = tid & 63;
    const int m = lane & 15, kg = lane >> 4;
    const int gm0 = blockIdx.x * 32;
    const int nb = wave * 96;
    const f32x4 zf = {0.f, 0.f, 0.f, 0.f};
    f32x4 acc[2][6];
#pragma unroll
    for (int mt = 0; mt < 2; ++mt)
#pragma unroll
        for (int tt = 0; tt < 6; ++tt) acc[mt][tt] = zf;

    for (int ks = 0; ks < 4; ++ks) {
        short8 ah[2];
#pragma unroll
        for (int mt = 0; mt < 2; ++mt) {
            int r = gm0 + mt * 16 + m;
            if (r >= M) r = M - 1;
            float tmp[8];
            VLOAD8(tmp, A + (size_t)r * 128 + ks * 32 + kg * 8);
            ah[mt] = tobf8(tmp);
        }
#pragma unroll
        for (int tt = 0; tt < 6; ++tt) {
            size_t wo = (size_t)(nb + tt * 16 + m) * 128 + ks * 32 + kg * 8;
            short8 bh = *(const short8*)(wh + wo);
            short8 bl = *(const short8*)(wl + wo);
#pragma unroll
            for (int mt = 0; mt < 2; ++mt)
                acc[mt][tt] = mfma2(ah[mt], bh, bl, acc[mt][tt]);
        }
    }
#pragma unroll
    for (int mt = 0; mt < 2; ++mt)
#pragma unroll
        for (int r = 0; r < 4; ++r) {
            int row = gm0 + mt * 16 + kg * 4 + r;
            if (row >= M) continue;
            int n = row / 3, v = row - n * 3;
            size_t fb = (size_t)n * 384 + (size_t)v * 128;           // vec1 f32
            size_t b2 = (size_t)n * 1024 + (size_t)v * 128;          // vec2 bf16
            size_t b3 = (size_t)n * 1024 + 384 + (size_t)v * 128;    // vec3 bf16
#pragma unroll
            for (int tt = 0; tt < 6; ++tt) {
                int col = nb + tt * 16 + m;
                float val = acc[mt][tt][r];
                int seg = col >> 7, k = col & 127;
                if (seg == 0)      vecp1[fb + k] = val;
                else if (seg == 1) bun[b2 + k] = f2bf_rne(val);
                else               bun[b3 + k] = f2bf_rne(val);
            }
        }
}

// ---------------------------------------------------------------------------
// hw-GEMM: [50000,128] @ [W1a|W1b]^T -> bundle bf16 (hw_row @768, hw_col @896)
// ---------------------------------------------------------------------------
__global__ void __launch_bounds__(256, 3)
gemm_hw(const float* __restrict__ A, int M,
        const short* __restrict__ wh, const short* __restrict__ wl,
        short* __restrict__ bun)
{
    const int tid = threadIdx.x, wave = tid >> 6, lane = tid & 63;
    const int m = lane & 15, kg = lane >> 4;
    const int gm0 = blockIdx.x * 32;
    const int nb = wave * 64;
    const f32x4 zf = {0.f, 0.f, 0.f, 0.f};
    f32x4 acc[2][4];
#pragma unroll
    for (int mt = 0; mt < 2; ++mt)
#pragma unroll
        for (int tt = 0; tt < 4; ++tt) acc[mt][tt] = zf;

    for (int ks = 0; ks < 4; ++ks) {
        short8 ah[2];
#pragma unroll
        for (int mt = 0; mt < 2; ++mt) {
            int r = gm0 + mt * 16 + m;
            if (r >= M) r = M - 1;
            float tmp[8];
            VLOAD8(tmp, A + (size_t)r * 128 + ks * 32 + kg * 8);
            ah[mt] = tobf8(tmp);
        }
#pragma unroll
        for (int tt = 0; tt < 4; ++tt) {
            size_t wo = (size_t)(nb + tt * 16 + m) * 128 + ks * 32 + kg * 8;
            short8 bh = *(const short8*)(wh + wo);
            short8 bl = *(const short8*)(wl + wo);
#pragma unroll
            for (int mt = 0; mt < 2; ++mt)
                acc[mt][tt] = mfma2(ah[mt], bh, bl, acc[mt][tt]);
        }
    }
#pragma unroll
    for (int mt = 0; mt < 2; ++mt)
#pragma unroll
        for (int r = 0; r < 4; ++r) {
            int row = gm0 + mt * 16 + kg * 4 + r;
            if (row >= M) continue;
#pragma unroll
            for (int tt = 0; tt < 4; ++tt) {
                int col = nb + tt * 16 + m;
                bun[(size_t)row * 1024 + 768 + col] = f2bf_rne(acc[mt][tt][r]);
            }
        }
}

// ---------------------------------------------------------------------------
// Fused o-GEMM + finalize: o = hagg@Wop+bop in-register; dh = vdot*o2+o3,
// dvec += vec3*o1. vdot = f32 vec1 x bf16 vec2 (bundle).
// ---------------------------------------------------------------------------
__global__ void __launch_bounds__(256, 3)
gemm_fin(const float* __restrict__ hagg, const float* __restrict__ vecp1,
         const short* __restrict__ bun,
         const short* __restrict__ wh, const short* __restrict__ wl,
         const float* __restrict__ bop, float* __restrict__ dh,
         float* __restrict__ dvec, int M)
{
    const int tid = threadIdx.x, wave = tid >> 6, lane = tid & 63;
    const int m = lane & 15, kg = lane >> 4;
    const int gm0 = blockIdx.x * 32;
    const int nb = wave * 32;
    const f32x4 zf = {0.f, 0.f, 0.f, 0.f};
    f32x4 acc[2][6];   // [mt][seg*2+tt]
#pragma unroll
    for (int mt = 0; mt < 2; ++mt)
#pragma unroll
        for (int t = 0; t < 6; ++t) acc[mt][t] = zf;

    for (int ks = 0; ks < 4; ++ks) {
        short8 ah[2];
#pragma unroll
        for (int mt = 0; mt < 2; ++mt) {
            int r = gm0 + mt * 16 + m;
            if (r >= M) r = M - 1;
            float tmp[8];
            VLOAD8(tmp, hagg + (size_t)r * 128 + ks * 32 + kg * 8);
            ah[mt] = tobf8(tmp);
        }
#pragma unroll
        for (int seg = 0; seg < 3; ++seg)
#pragma unroll
            for (int tt = 0; tt < 2; ++tt) {
                size_t wo = (size_t)(seg * 128 + nb + tt * 16 + m) * 128 + ks * 32 + kg * 8;
                short8 bh = *(const short8*)(wh + wo);
                short8 bl = *(const short8*)(wl + wo);
#pragma unroll
                for (int mt = 0; mt < 2; ++mt)
                    acc[mt][seg * 2 + tt] = mfma2(ah[mt], bh, bl, acc[mt][seg * 2 + tt]);
            }
    }
    float bo[3][2];
#pragma unroll
    for (int seg = 0; seg < 3; ++seg)
#pragma unroll
        for (int tt = 0; tt < 2; ++tt) bo[seg][tt] = bop[seg * 128 + nb + tt * 16 + m];

#pragma unroll
    for (int mt = 0; mt < 2; ++mt)
#pragma unroll
        for (int r = 0; r < 4; ++r) {
            int row = gm0 + mt * 16 + kg * 4 + r;
            if (row >= M) continue;
            size_t b = (size_t)row * 384;          // vec1 f32
            size_t b2 = (size_t)row * 1024;        // vec2 bf16
            size_t bb = (size_t)row * 1024 + 384;  // vec3 bf16
#pragma unroll
            for (int tt = 0; tt < 2; ++tt) {
                int k = nb + tt * 16 + m;
                float o1 = acc[mt][0 * 2 + tt][r] + bo[0][tt];
                float o2 = acc[mt][1 * 2 + tt][r] + bo[1][tt];
                float o3 = acc[mt][2 * 2 + tt][r] + bo[2][tt];
                float vd = vecp1[b + k]       * bf2f(bun[b2 + k])
                         + vecp1[b + 128 + k] * bf2f(bun[b2 + 128 + k])
                         + vecp1[b + 256 + k] * bf2f(bun[b2 + 256 + k]);
                dh[(size_t)row * 128 + k] = vd * o2 + o3;
                size_t db = (size_t)row * 384 + k;
                dvec[db]       += bf2f(bun[bb + k])       * o1;
                dvec[db + 128] += bf2f(bun[bb + 128 + k]) * o1;
                dvec[db + 256] += bf2f(bun[bb + 256 + k]) * o1;
            }
        }
}

// ---------------------------------------------------------------------------
// Fused edge kernel over SORTED edges. 64 edges/block, 4 waves, 4 M-tiles.
// R4 showed latency-bound (all pipes <25%, occ 43%, BW 1.77<2.3 TB/s ceiling):
// single-bf16 A (mfma2) halves MFMA+LDS -> ~19.4KB -> 8 blocks/CU = 32 waves
// (keeps 64-edge reuse/atomic structure, unlike R2's 32-edge regression).
// ---------------------------------------------------------------------------
__global__ void __launch_bounds__(256, 8)
edge_kernel(const float* __restrict__ vecp1, const short* __restrict__ bun,
            const float* __restrict__ coord, const int* __restrict__ eidx,
            const float* __restrict__ eattr, const short* __restrict__ wt,
            const int* __restrict__ perm,
            const float* __restrict__ b1, const float* __restrict__ b2,
            const float* __restrict__ b3,
            float* __restrict__ hagg, float* __restrict__ dvec)
{
    // union: ab dbuf {cab[2][64][40]} = 10240B ; x {xh[64][136]} = 17408B
    __shared__ __align__(16) unsigned char smem[17408];
    short (*xh)[136]  = (short(*)[136])(&smem[0]);
    __shared__ int   s_row[64], s_col[64], s_es[64];
    __shared__ float s_xij[64][3];
    __shared__ float s_d[64];

    // bijective XCD swizzle: each XCD owns a contiguous logical edge range.
    const int nwg = gridDim.x;
    const int q8 = nwg >> 3, r8 = nwg & 7;
    const int xcd = blockIdx.x & 7, loc = blockIdx.x >> 3;
    const int lb = (xcd < r8 ? xcd * (q8 + 1) : r8 * (q8 + 1) + (xcd - r8) * q8) + loc;

    const int tid = threadIdx.x;
    const int wave = tid >> 6, lane = tid & 63;
    const int m = lane & 15, kg = lane >> 4;
    const int nb = wave * 32;
    const int eb = lb * 64;
    const int be = tid >> 2;
    const int bq = (tid & 3) * 8;

    if (tid < 64) {
        int es = perm[eb + tid];
        int r = eidx[es], c = eidx[NE + es];
        s_es[tid] = es; s_row[tid] = r; s_col[tid] = c;
        float x0 = coord[r * 3 + 0] - coord[c * 3 + 0];
        float x1 = coord[r * 3 + 1] - coord[c * 3 + 1];
        float x2 = coord[r * 3 + 2] - coord[c * 3 + 2];
        s_xij[tid][0] = x0; s_xij[tid][1] = x1; s_xij[tid][2] = x2;
        s_d[tid] = sqrtf(x0 * x0 + x1 * x1 + x2 * x2 + 1e-8f);
    }
    __syncthreads();

    const f32x4 zf = {0.f, 0.f, 0.f, 0.f};
    const float delta = 5.0f / 31.0f;
    const float coeff = -0.5f / (delta * delta);
    const int brow = s_row[be], bcol = s_col[be], bes = s_es[be];

    float pA[8], pC[8], pE[8];
    short8 bB, bD, bF;
    auto issue = [&](int ks) {
        if (ks < 4) {
            int kk = ks * 32 + bq;
            const float* vr = vecp1 + (size_t)brow * 384 + kk;    // vec1 f32, stride 128/v
            const short* vc = bun + (size_t)bcol * 1024 + kk;     // vec2 bf16, stride 128/v
            VLOAD8(pA, vr); VLOAD8(pC, vr + 128); VLOAD8(pE, vr + 256);
            bB = *(const short8*)(vc);
            bD = *(const short8*)(vc + 128);
            bF = *(const short8*)(vc + 256);
        } else if (ks == 5) {
            if (bq < 16) VLOAD8(pA, eattr + (size_t)bes * 16 + bq);
        }
    };
    auto commit = [&](int ks, int buf) {
        short (*cab)[40] = (short(*)[40])(&smem[(size_t)buf * 5120]);
        float tmp[8];
        if (ks < 4) {
#pragma unroll
            for (int j = 0; j < 8; ++j)
                tmp[j] = pA[j] * bf2f(bB[j]) + pC[j] * bf2f(bD[j]) + pE[j] * bf2f(bF[j]);
        } else if (ks == 4) {
            float dd = s_d[be];
#pragma unroll
            for (int j = 0; j < 8; ++j) {
                float x = dd - (float)(bq + j) * delta;
                tmp[j] = __expf(coeff * x * x);
            }
        } else {
#pragma unroll
            for (int j = 0; j < 8; ++j) tmp[j] = (bq < 16) ? pA[j] : 0.f;
        }
        *(short8*)&cab[be][bq] = tobf8(tmp);
    };

    // ---------------- GEMM1: [64e x 192] @ W1cde (dbuf staging) ----------
    f32x4 acc[4][2];
#pragma unroll
    for (int mt = 0; mt < 4; ++mt) { acc[mt][0] = zf; acc[mt][1] = zf; }

    issue(0); commit(0, 0);
    __syncthreads();
    for (int ks = 0; ks < 6; ++ks) {
        if (ks < 5) issue(ks + 1);
        const short (*rab)[40] = (const short(*)[40])(&smem[(size_t)(ks & 1) * 5120]);
        short8 ah4[4];
#pragma unroll
        for (int mt = 0; mt < 4; ++mt)
            ah4[mt] = *(const short8*)&rab[mt * 16 + m][kg * 8];
#pragma unroll
        for (int tt = 0; tt < 2; ++tt) {
            size_t wo = (size_t)(nb + tt * 16 + m) * 192 + ks * 32 + kg * 8;
            short8 bh = *(const short8*)(wt + O_W1H + wo);
            short8 bl = *(const short8*)(wt + O_W1L + wo);
#pragma unroll
            for (int mt = 0; mt < 4; ++mt)
                acc[mt][tt] = mfma2(ah4[mt], bh, bl, acc[mt][tt]);
        }
        if (ks < 5) commit(ks + 1, (ks + 1) & 1);
        __syncthreads();
    }
    // ab buffers dead; xh (same memory) becomes live

    // epilogue1: += hw[row] + hw[col] + b1 (bf16 bundle), silu -> xh
    {
        float b1v[2] = { b1[nb + m], b1[nb + 16 + m] };
#pragma unroll
        for (int mt = 0; mt < 4; ++mt) {
            float hb[4][4];
#pragma unroll
            for (int r = 0; r < 4; ++r) {
                int e = mt * 16 + kg * 4 + r;
                const short* hr = bun + (size_t)s_row[e] * 1024 + 768;
                const short* hc = bun + (size_t)s_col[e] * 1024 + 896;
                hb[r][0] = bf2f(hr[nb + m]);      hb[r][1] = bf2f(hc[nb + m]);
                hb[r][2] = bf2f(hr[nb + 16 + m]); hb[r][3] = bf2f(hc[nb + 16 + m]);
            }
#pragma unroll
            for (int r = 0; r < 4; ++r) {
                int e = mt * 16 + kg * 4 + r;
#pragma unroll
                for (int tt = 0; tt < 2; ++tt) {
                    int n = nb + tt * 16 + m;
                    float v = acc[mt][tt][r] + hb[r][tt * 2] + hb[r][tt * 2 + 1] + b1v[tt];
                    float sv = v * __builtin_amdgcn_rcpf(1.f + __expf(-v));
                    xh[e][n] = f2bf_rne(sv);
                }
            }
        }
    }
    __syncthreads();

    // ---------------- GEMM2: x1 @ W2t -> x2 ----------------
#pragma unroll
    for (int mt = 0; mt < 4; ++mt) { acc[mt][0] = zf; acc[mt][1] = zf; }
    for (int ks = 0; ks < 4; ++ks) {
        short8 ah4[4];
#pragma unroll
        for (int mt = 0; mt < 4; ++mt)
            ah4[mt] = *(const short8*)&xh[mt * 16 + m][ks * 32 + kg * 8];
#pragma unroll
        for (int tt = 0; tt < 2; ++tt) {
            size_t wo = (size_t)(nb + tt * 16 + m) * 128 + ks * 32 + kg * 8;
            short8 bh = *(const short8*)(wt + O_W2H + wo);
            short8 bl = *(const short8*)(wt + O_W2L + wo);
#pragma unroll
            for (int mt = 0; mt < 4; ++mt)
                acc[mt][tt] = mfma2(ah4[mt], bh, bl, acc[mt][tt]);
        }
    }
    {
        float b2v[2] = { b2[nb + m], b2[nb + 16 + m] };
#pragma unroll
        for (int mt = 0; mt < 4; ++mt)
#pragma unroll
            for (int tt = 0; tt < 2; ++tt)
#pragma unroll
                for (int r = 0; r < 4; ++r) {
                    float v = acc[mt][tt][r] + b2v[tt];
                    acc[mt][tt][r] = v * __builtin_amdgcn_rcpf(1.f + __expf(-v));
                }
    }
    __syncthreads();
#pragma unroll
    for (int mt = 0; mt < 4; ++mt)
#pragma unroll
        for (int tt = 0; tt < 2; ++tt)
#pragma unroll
            for (int r = 0; r < 4; ++r) {
                int e = mt * 16 + kg * 4 + r;
                int n = nb + tt * 16 + m;
                xh[e][n] = f2bf_rne(acc[mt][tt][r]);
            }
    __syncthreads();

    // ---------------- GEMM3: x2 @ W3t (3 col-tiles) + combined scatter ----
    float msgv[4][2][4];
    for (int c = 0; c < 3; ++c) {
        f32x4 a3[4][2];
#pragma unroll
        for (int mt = 0; mt < 4; ++mt) { a3[mt][0] = zf; a3[mt][1] = zf; }
        for (int ks = 0; ks < 4; ++ks) {
            short8 ah4[4];
#pragma unroll
            for (int mt = 0; mt < 4; ++mt)
                ah4[mt] = *(const short8*)&xh[mt * 16 + m][ks * 32 + kg * 8];
#pragma unroll
            for (int tt = 0; tt < 2; ++tt) {
                size_t wo = (size_t)(c * 128 + nb + tt * 16 + m) * 128 + ks * 32 + kg * 8;
                short8 bh = *(const short8*)(wt + O_W3H + wo);
                short8 bl = *(const short8*)(wt + O_W3L + wo);
#pragma unroll
                for (int mt = 0; mt < 4; ++mt)
                    a3[mt][tt] = mfma2(ah4[mt], bh, bl, a3[mt][tt]);
            }
        }
        float bv[2] = { b3[c * 128 + nb + m], b3[c * 128 + nb + 16 + m] };
        const int n0 = nb + m, n1 = nb + 16 + m;
        if (c == 0) {          // msg_h -> h_aggr[row], run-combined
            int cur = s_row[kg * 4];
            float s0 = 0.f, s1 = 0.f;
#pragma unroll
            for (int mt = 0; mt < 4; ++mt)
#pragma unroll
                for (int r = 0; r < 4; ++r) {
                    int rr = s_row[mt * 16 + kg * 4 + r];
                    float v0 = a3[mt][0][r] + bv[0];
                    float v1 = a3[mt][1][r] + bv[1];
                    if (rr != cur) {
                        atomicAdd(&hagg[(size_t)cur * 128 + n0], s0);
                        atomicAdd(&hagg[(size_t)cur * 128 + n1], s1);
                        cur = rr; s0 = 0.f; s1 = 0.f;
                    }
                    s0 += v0; s1 += v1;
                }
            atomicAdd(&hagg[(size_t)cur * 128 + n0], s0);
            atomicAdd(&hagg[(size_t)cur * 128 + n1], s1);
        } else if (c == 1) {
#pragma unroll
            for (int mt = 0; mt < 4; ++mt)
#pragma unroll
                for (int tt = 0; tt < 2; ++tt)
#pragma unroll
                    for (int r = 0; r < 4; ++r)
                        msgv[mt][tt][r] = a3[mt][tt][r] + bv[tt];
        } else {               // msg_x: dvec[row] += vec3[col]*msg_v + x_ij*msg_x
            int cur = s_row[kg * 4];
            float sd[6] = {0.f, 0.f, 0.f, 0.f, 0.f, 0.f};
#pragma unroll
            for (int mt = 0; mt < 4; ++mt) {
                float v3b[4][6];   // pass 1: batch scattered bf16 loads
#pragma unroll
                for (int r = 0; r < 4; ++r) {
                    int e = mt * 16 + kg * 4 + r;
                    const short* v3 = bun + (size_t)s_col[e] * 1024 + 384;
                    v3b[r][0] = bf2f(v3[n0]); v3b[r][1] = bf2f(v3[128 + n0]); v3b[r][2] = bf2f(v3[256 + n0]);
                    v3b[r][3] = bf2f(v3[n1]); v3b[r][4] = bf2f(v3[128 + n1]); v3b[r][5] = bf2f(v3[256 + n1]);
                }
#pragma unroll
                for (int r = 0; r < 4; ++r) {
                    int e = mt * 16 + kg * 4 + r;
                    int rr = s_row[e];
                    if (rr != cur) {
                        float* dst = dvec + (size_t)cur * 384;
                        atomicAdd(dst + n0,       sd[0]);
                        atomicAdd(dst + 128 + n0, sd[1]);
                        atomicAdd(dst + 256 + n0, sd[2]);
                        atomicAdd(dst + n1,       sd[3]);
                        atomicAdd(dst + 128 + n1, sd[4]);
                        atomicAdd(dst + 256 + n1, sd[5]);
                        cur = rr;
#pragma unroll
                        for (int q = 0; q < 6; ++q) sd[q] = 0.f;
                    }
                    const float xj0 = s_xij[e][0], xj1 = s_xij[e][1], xj2 = s_xij[e][2];
                    float mx0 = a3[mt][0][r] + bv[0], mx1 = a3[mt][1][r] + bv[1];
                    float mv0 = msgv[mt][0][r],       mv1 = msgv[mt][1][r];
                    sd[0] += v3b[r][0] * mv0 + xj0 * mx0;
                    sd[1] += v3b[r][1] * mv0 + xj1 * mx0;
                    sd[2] += v3b[r][2] * mv0 + xj2 * mx0;
                    sd[3] += v3b[r][3] * mv1 + xj0 * mx1;
                    sd[4] += v3b[r][4] * mv1 + xj1 * mx1;
                    sd[5] += v3b[r][5] * mv1 + xj2 * mx1;
                }
            }
            float* dst = dvec + (size_t)cur * 384;
            atomicAdd(dst + n0,       sd[0]);
            atomicAdd(dst + 128 + n0, sd[1]);
            atomicAdd(dst + 256 + n0, sd[2]);
            atomicAdd(dst + n1,       sd[3]);
            atomicAdd(dst + 128 + n1, sd[4]);
            atomicAdd(dst + 256 + n1, sd[5]);
        }
    }
}

// ---------------------------------------------------------------------------
extern "C" void kernel_launch(void* const* d_in, const int* in_sizes, int n_in,
                              void* d_out, int out_size, void* d_ws, size_t ws_size,
                              hipStream_t stream)
{
    const float* h     = (const float*)d_in[0];
    const float* vec   = (const float*)d_in[1];
    const float* coord = (const float*)d_in[2];
    const int*   eidx  = (const int*)  d_in[3];
    const float* eattr = (const float*)d_in[4];
    const float* Wvp   = (const float*)d_in[5];
    const float* W1    = (const float*)d_in[6];
    const float* b1    = (const float*)d_in[7];
    const float* W2    = (const float*)d_in[8];
    const float* b2    = (const float*)d_in[9];
    const float* W3    = (const float*)d_in[10];
    const float* b3    = (const float*)d_in[11];
    const float* Wop   = (const float*)d_in[12];
    const float* bop   = (const float*)d_in[13];

    if (ws_size < WS_FLOATS * sizeof(float)) return;

    float* ws    = (float*)d_ws;
    float* vecp1 = ws + OFF_VECP1;
    short* bun   = (short*)(ws + OFF_BUN);
    float* hagg  = ws + OFF_HAGG;
    short* wt    = (short*)(ws + OFF_WT);
    int*   perm  = (int*)(ws + OFF_PERM);
    int*   deg   = (int*)(ws + OFF_DEG);
    int*   cur   = (int*)(ws + OFF_CUR);
    float* dh    = (float*)d_out;
    float* dvec  = (float*)d_out + (size_t)NN * HID;

    dim3 b256(256);
    hipMemsetAsync(deg, 0, NN * sizeof(int), stream);
    misc_kernel<<<25000, b256, 0, stream>>>(W1, W2, W3, Wvp, Wop, wt, eidx, deg, hagg, dvec);
    sort_scan<<<1, 1024, 0, stream>>>(deg, cur);
    sort_scatter<<<1563, b256, 0, stream>>>(eidx, cur, perm);
    // vecp1 (f32 vec1) + bundle vec2/vec3 (bf16)
    gemm_vp<<<4688, b256, 0, stream>>>(vec, 150000, wt + O_VPH, wt + O_VPL, vecp1, bun);
    // bundle hw_row/hw_col (bf16)
    gemm_hw<<<1563, b256, 0, stream>>>(h, 50000, wt + O_HWH, wt + O_HWL, bun);
    // fused per-edge MLP + combined scatter (sorted order, 64 edges/block)
    edge_kernel<<<6250, b256, 0, stream>>>(vecp1, bun, coord, eidx, eattr, wt, perm,
                                           b1, b2, b3, hagg, dvec);
    // fused o-GEMM + finalize
    gemm_fin<<<1563, b256, 0, stream>>>(hagg, vecp1, bun, wt + O_OPH, wt + O_OPL,
                                        bop, dh, dvec, 50000);
}

// Round 6
// 1195.716 us; speedup vs baseline: 1.4264x; 1.4264x over previous
//
#include <hip/hip_runtime.h>
#include <math.h>

// Problem constants
constexpr int NN    = 50000;
constexpr int NE    = 400000;
constexpr int HID   = 128;

// Workspace layout (float offsets)
// vecb1: [N][3][128] bf16 (vec1)                             9.6M floats (19.2M shorts)
// bun:   [N][1024] bf16 {vec2 | vec3 | hw_row | hw_col}     25.6M floats (51.2M shorts)
// hagg:  [N][128] f32                                         6.4M floats
constexpr size_t OFF_VECB1 = 0;
constexpr size_t OFF_BUN  = 9600000;
constexpr size_t OFF_HAGG = 35200000;
constexpr size_t OFF_WT   = 83200000;     // weights, 442368 shorts
constexpr size_t OFF_PERM = 83421184;     // int[400000]
constexpr size_t OFF_DEG  = 83821184;     // int[50000]
constexpr size_t OFF_CUR  = 83871184;     // int[50000]
constexpr size_t WS_FLOATS = 83921184;    // ~335.7 MB

// split-bf16 weight offsets (shorts, within wt region) — weights stay split
constexpr size_t O_HWH = 0;        // [256n][128k]
constexpr size_t O_HWL = 32768;
constexpr size_t O_W1H = 65536;    // [128n][192k]
constexpr size_t O_W1L = 90112;
constexpr size_t O_W2H = 114688;   // [128n][128k]
constexpr size_t O_W2L = 131072;
constexpr size_t O_W3H = 147456;   // [384n][128k]
constexpr size_t O_W3L = 196608;
constexpr size_t O_VPH = 245760;   // [384n][128k]
constexpr size_t O_VPL = 294912;
constexpr size_t O_OPH = 344064;   // [384n][128k]
constexpr size_t O_OPL = 393216;

typedef __attribute__((ext_vector_type(8))) short short8;
typedef __attribute__((ext_vector_type(4))) float f32x4;

__device__ __forceinline__ short f2bf_rne(float f) {
    unsigned u = __float_as_uint(f);
    u += 0x7fffu + ((u >> 16) & 1u);
    return (short)(u >> 16);
}
__device__ __forceinline__ float bf2f(short h) {
    return __uint_as_float(((unsigned)(unsigned short)h) << 16);
}
__device__ __forceinline__ short8 tobf8(const float* t) {
    short8 r;
#pragma unroll
    for (int j = 0; j < 8; ++j) r[j] = f2bf_rne(t[j]);
    return r;
}
// 2-term product: A single bf16, weights split bf16 (bh+bl).
__device__ __forceinline__ f32x4 mfma2(short8 a, short8 bh, short8 bl, f32x4 c) {
    c = __builtin_amdgcn_mfma_f32_16x16x32_bf16(a, bh, c, 0, 0, 0);
    c = __builtin_amdgcn_mfma_f32_16x16x32_bf16(a, bl, c, 0, 0, 0);
    return c;
}

#define VLOAD8(dst, src) do { \
    *(float4*)&(dst)[0] = *(const float4*)(src); \
    *(float4*)&(dst)[4] = *(const float4*)((src) + 4); } while (0)

// ---------------------------------------------------------------------------
// misc: zero hagg/dvec (grid 25000) + wprep (blocks <864) + sort hist (<1563)
// ---------------------------------------------------------------------------
__global__ void misc_kernel(const float* __restrict__ W1, const float* __restrict__ W2,
                            const float* __restrict__ W3, const float* __restrict__ Wvp,
                            const float* __restrict__ Wop, short* __restrict__ wt,
                            const int* __restrict__ eidx, int* __restrict__ deg,
                            float* __restrict__ hagg, float* __restrict__ dvec)
{
    const int bid = blockIdx.x;
    const int idx = bid * 256 + threadIdx.x;
    {
        int n = idx >> 7, k = idx & 127;
        hagg[idx] = 0.f;
        size_t db = (size_t)n * 384 + k;
        dvec[db] = 0.f; dvec[db + 128] = 0.f; dvec[db + 256] = 0.f;
    }
    if (bid < 864) {   // weight split/transpose, idx < 221184
        float v; size_t oh, ol;
        if (idx < 32768) {
            int j = idx >> 7, k = idx & 127;
            v = (j < 128) ? W1[(size_t)k * 128 + j] : W1[(size_t)(128 + k) * 128 + (j - 128)];
            oh = O_HWH + idx; ol = O_HWL + idx;
        } else if (idx < 57344) {
            int l = idx - 32768; int n = l / 192, k = l - n * 192;
            int r = (k < 128) ? (288 + k) : (k < 160) ? (256 + k - 128) : (k < 176) ? (416 + k - 160) : -1;
            v = (r < 0) ? 0.f : W1[(size_t)r * 128 + n];
            oh = O_W1H + l; ol = O_W1L + l;
        } else if (idx < 73728) {
            int l = idx - 57344; int n = l >> 7, k = l & 127;
            v = W2[(size_t)k * 128 + n];
            oh = O_W2H + l; ol = O_W2L + l;
        } else if (idx < 122880) {
            int l = idx - 73728; int n = l >> 7, k = l & 127;
            v = W3[(size_t)k * 384 + n];
            oh = O_W3H + l; ol = O_W3L + l;
        } else if (idx < 172032) {
            int l = idx - 122880; int n = l >> 7, k = l & 127;
            v = Wvp[(size_t)k * 384 + n];
            oh = O_VPH + l; ol = O_VPL + l;
        } else {
            int l = idx - 172032; int n = l >> 7, k = l & 127;
            v = Wop[(size_t)k * 384 + n];
            oh = O_OPH + l; ol = O_OPL + l;
        }
        short hi = f2bf_rne(v);
        wt[oh] = hi;
        wt[ol] = f2bf_rne(v - bf2f(hi));
    }
    if (bid < 1563 && idx < NE)   // degree histogram
        atomicAdd(&deg[eidx[idx]], 1);
}

__global__ void __launch_bounds__(1024)
sort_scan(const int* __restrict__ deg, int* __restrict__ cursor)
{
    __shared__ int part[1024];
    const int tid = threadIdx.x;
    const int base = tid * 49;
    int s = 0;
#pragma unroll 7
    for (int j = 0; j < 49; ++j) {
        int i = base + j;
        if (i < NN) s += deg[i];
    }
    part[tid] = s;
    __syncthreads();
    for (int off = 1; off < 1024; off <<= 1) {
        int v = (tid >= off) ? part[tid - off] : 0;
        __syncthreads();
        part[tid] += v;
        __syncthreads();
    }
    int run = part[tid] - s;
    for (int j = 0; j < 49; ++j) {
        int i = base + j;
        if (i < NN) { cursor[i] = run; run += deg[i]; }
    }
}

__global__ void sort_scatter(const int* __restrict__ eidx, int* __restrict__ cursor,
                             int* __restrict__ perm)
{
    int e = blockIdx.x * 256 + threadIdx.x;
    if (e < NE) {
        int pos = atomicAdd(&cursor[eidx[e]], 1);
        perm[pos] = e;
    }
}

// ---------------------------------------------------------------------------
// vp-GEMM: [150000,128] @ Wvp^T -> vec1 bf16 (vecb1) + vec2/vec3 bf16 (bundle)
// ---------------------------------------------------------------------------
__global__ void __launch_bounds__(256, 3)
gemm_vp(const float* __restrict__ A, int M,
        const short* __restrict__ wh, const short* __restrict__ wl,
        short* __restrict__ vecb1, short* __restrict__ bun)
{
    const int tid = threadIdx.x, wave = tid >> 6, lane = tid & 63;
    const int m = lane & 15, kg = lane >> 4;
    const int gm0 = blockIdx.x * 32;
    const int nb = wave * 96;
    const f32x4 zf = {0.f, 0.f, 0.f, 0.f};
    f32x4 acc[2][6];
#pragma unroll
    for (int mt = 0; mt < 2; ++mt)
#pragma unroll
        for (int tt = 0; tt < 6; ++tt) acc[mt][tt] = zf;

    for (int ks = 0; ks < 4; ++ks) {
        short8 ah[2];
#pragma unroll
        for (int mt = 0; mt < 2; ++mt) {
            int r = gm0 + mt * 16 + m;
            if (r >= M) r = M - 1;
            float tmp[8];
            VLOAD8(tmp, A + (size_t)r * 128 + ks * 32 + kg * 8);
            ah[mt] = tobf8(tmp);
        }
#pragma unroll
        for (int tt = 0; tt < 6; ++tt) {
            size_t wo = (size_t)(nb + tt * 16 + m) * 128 + ks * 32 + kg * 8;
            short8 bh = *(const short8*)(wh + wo);
            short8 bl = *(const short8*)(wl + wo);
#pragma unroll
            for (int mt = 0; mt < 2; ++mt)
                acc[mt][tt] = mfma2(ah[mt], bh, bl, acc[mt][tt]);
        }
    }
#pragma unroll
    for (int mt = 0; mt < 2; ++mt)
#pragma unroll
        for (int r = 0; r < 4; ++r) {
            int row = gm0 + mt * 16 + kg * 4 + r;
            if (row >= M) continue;
            int n = row / 3, v = row - n * 3;
            size_t f1 = (size_t)n * 384 + (size_t)v * 128;           // vec1 bf16
            size_t b2 = (size_t)n * 1024 + (size_t)v * 128;          // vec2 bf16
            size_t b3 = (size_t)n * 1024 + 384 + (size_t)v * 128;    // vec3 bf16
#pragma unroll
            for (int tt = 0; tt < 6; ++tt) {
                int col = nb + tt * 16 + m;
                float val = acc[mt][tt][r];
                int seg = col >> 7, k = col & 127;
                if (seg == 0)      vecb1[f1 + k] = f2bf_rne(val);
                else if (seg == 1) bun[b2 + k] = f2bf_rne(val);
                else               bun[b3 + k] = f2bf_rne(val);
            }
        }
}

// ---------------------------------------------------------------------------
// hw-GEMM: [50000,128] @ [W1a|W1b]^T -> bundle bf16 (hw_row @768, hw_col @896)
// ---------------------------------------------------------------------------
__global__ void __launch_bounds__(256, 3)
gemm_hw(const float* __restrict__ A, int M,
        const short* __restrict__ wh, const short* __restrict__ wl,
        short* __restrict__ bun)
{
    const int tid = threadIdx.x, wave = tid >> 6, lane = tid & 63;
    const int m = lane & 15, kg = lane >> 4;
    const int gm0 = blockIdx.x * 32;
    const int nb = wave * 64;
    const f32x4 zf = {0.f, 0.f, 0.f, 0.f};
    f32x4 acc[2][4];
#pragma unroll
    for (int mt = 0; mt < 2; ++mt)
#pragma unroll
        for (int tt = 0; tt < 4; ++tt) acc[mt][tt] = zf;

    for (int ks = 0; ks < 4; ++ks) {
        short8 ah[2];
#pragma unroll
        for (int mt = 0; mt < 2; ++mt) {
            int r = gm0 + mt * 16 + m;
            if (r >= M) r = M - 1;
            float tmp[8];
            VLOAD8(tmp, A + (size_t)r * 128 + ks * 32 + kg * 8);
            ah[mt] = tobf8(tmp);
        }
#pragma unroll
        for (int tt = 0; tt < 4; ++tt) {
            size_t wo = (size_t)(nb + tt * 16 + m) * 128 + ks * 32 + kg * 8;
            short8 bh = *(const short8*)(wh + wo);
            short8 bl = *(const short8*)(wl + wo);
#pragma unroll
            for (int mt = 0; mt < 2; ++mt)
                acc[mt][tt] = mfma2(ah[mt], bh, bl, acc[mt][tt]);
        }
    }
#pragma unroll
    for (int mt = 0; mt < 2; ++mt)
#pragma unroll
        for (int r = 0; r < 4; ++r) {
            int row = gm0 + mt * 16 + kg * 4 + r;
            if (row >= M) continue;
#pragma unroll
            for (int tt = 0; tt < 4; ++tt) {
                int col = nb + tt * 16 + m;
                bun[(size_t)row * 1024 + 768 + col] = f2bf_rne(acc[mt][tt][r]);
            }
        }
}

// ---------------------------------------------------------------------------
// Fused o-GEMM + finalize: o = hagg@Wop+bop in-register; dh = vdot*o2+o3,
// dvec += vec3*o1. vdot = bf16 vec1 x bf16 vec2.
// ---------------------------------------------------------------------------
__global__ void __launch_bounds__(256, 3)
gemm_fin(const float* __restrict__ hagg, const short* __restrict__ vecb1,
         const short* __restrict__ bun,
         const short* __restrict__ wh, const short* __restrict__ wl,
         const float* __restrict__ bop, float* __restrict__ dh,
         float* __restrict__ dvec, int M)
{
    const int tid = threadIdx.x, wave = tid >> 6, lane = tid & 63;
    const int m = lane & 15, kg = lane >> 4;
    const int gm0 = blockIdx.x * 32;
    const int nb = wave * 32;
    const f32x4 zf = {0.f, 0.f, 0.f, 0.f};
    f32x4 acc[2][6];   // [mt][seg*2+tt]
#pragma unroll
    for (int mt = 0; mt < 2; ++mt)
#pragma unroll
        for (int t = 0; t < 6; ++t) acc[mt][t] = zf;

    for (int ks = 0; ks < 4; ++ks) {
        short8 ah[2];
#pragma unroll
        for (int mt = 0; mt < 2; ++mt) {
            int r = gm0 + mt * 16 + m;
            if (r >= M) r = M - 1;
            float tmp[8];
            VLOAD8(tmp, hagg + (size_t)r * 128 + ks * 32 + kg * 8);
            ah[mt] = tobf8(tmp);
        }
#pragma unroll
        for (int seg = 0; seg < 3; ++seg)
#pragma unroll
            for (int tt = 0; tt < 2; ++tt) {
                size_t wo = (size_t)(seg * 128 + nb + tt * 16 + m) * 128 + ks * 32 + kg * 8;
                short8 bh = *(const short8*)(wh + wo);
                short8 bl = *(const short8*)(wl + wo);
#pragma unroll
                for (int mt = 0; mt < 2; ++mt)
                    acc[mt][seg * 2 + tt] = mfma2(ah[mt], bh, bl, acc[mt][seg * 2 + tt]);
            }
    }
    float bo[3][2];
#pragma unroll
    for (int seg = 0; seg < 3; ++seg)
#pragma unroll
        for (int tt = 0; tt < 2; ++tt) bo[seg][tt] = bop[seg * 128 + nb + tt * 16 + m];

#pragma unroll
    for (int mt = 0; mt < 2; ++mt)
#pragma unroll
        for (int r = 0; r < 4; ++r) {
            int row = gm0 + mt * 16 + kg * 4 + r;
            if (row >= M) continue;
            size_t f1 = (size_t)row * 384;         // vec1 bf16
            size_t b2 = (size_t)row * 1024;        // vec2 bf16
            size_t bb = (size_t)row * 1024 + 384;  // vec3 bf16
#pragma unroll
            for (int tt = 0; tt < 2; ++tt) {
                int k = nb + tt * 16 + m;
                float o1 = acc[mt][0 * 2 + tt][r] + bo[0][tt];
                float o2 = acc[mt][1 * 2 + tt][r] + bo[1][tt];
                float o3 = acc[mt][2 * 2 + tt][r] + bo[2][tt];
                float vd = bf2f(vecb1[f1 + k])       * bf2f(bun[b2 + k])
                         + bf2f(vecb1[f1 + 128 + k]) * bf2f(bun[b2 + 128 + k])
                         + bf2f(vecb1[f1 + 256 + k]) * bf2f(bun[b2 + 256 + k]);
                dh[(size_t)row * 128 + k] = vd * o2 + o3;
                size_t db = (size_t)row * 384 + k;
                dvec[db]       += bf2f(bun[bb + k])       * o1;
                dvec[db + 128] += bf2f(bun[bb + 128 + k]) * o1;
                dvec[db + 256] += bf2f(bun[bb + 256 + k]) * o1;
            }
        }
}

// ---------------------------------------------------------------------------
// Fused edge kernel over SORTED edges. 64 edges/block, 4 waves, 4 M-tiles.
// OCCUPANCY IS PINNED TO 4 BLOCKS/CU via LDS padding: R5 showed an L3
// bistability — at 8 blk/CU the in-flight col working set (235MB) + inter-
// touch set (~130MB) exceeds the 256MB L3 -> bytes 1.19->3.43 GB, dur +62%.
// 4 blk/CU sits inside the good equilibrium. Only ~17.4KB of LDS is used.
// ---------------------------------------------------------------------------
__global__ void __launch_bounds__(256, 4)
edge_kernel(const short* __restrict__ vecb1, const short* __restrict__ bun,
            const float* __restrict__ coord, const int* __restrict__ eidx,
            const float* __restrict__ eattr, const short* __restrict__ wt,
            const int* __restrict__ perm,
            const float* __restrict__ b1, const float* __restrict__ b2,
            const float* __restrict__ b3,
            float* __restrict__ hagg, float* __restrict__ dvec)
{
    // used: ab dbuf {cab[2][64][40]} = 10240B ; x {xh[64][136]} = 17408B
    // declared 36864B on purpose (occupancy governor -> 4 blocks/CU).
    __shared__ __align__(16) unsigned char smem[36864];
    short (*xh)[136]  = (short(*)[136])(&smem[0]);
    __shared__ int   s_row[64], s_col[64], s_es[64];
    __shared__ float s_xij[64][3];
    __shared__ float s_d[64];

    // bijective XCD swizzle: each XCD owns a contiguous logical edge range.
    const int nwg = gridDim.x;
    const int q8 = nwg >> 3, r8 = nwg & 7;
    const int xcd = blockIdx.x & 7, loc = blockIdx.x >> 3;
    const int lb = (xcd < r8 ? xcd * (q8 + 1) : r8 * (q8 + 1) + (xcd - r8) * q8) + loc;

    const int tid = threadIdx.x;
    const int wave = tid >> 6, lane = tid & 63;
    const int m = lane & 15, kg = lane >> 4;
    const int nb = wave * 32;
    const int eb = lb * 64;
    const int be = tid >> 2;
    const int bq = (tid & 3) * 8;

    if (tid < 64) {
        int es = perm[eb + tid];
        int r = eidx[es], c = eidx[NE + es];
        s_es[tid] = es; s_row[tid] = r; s_col[tid] = c;
        float x0 = coord[r * 3 + 0] - coord[c * 3 + 0];
        float x1 = coord[r * 3 + 1] - coord[c * 3 + 1];
        float x2 = coord[r * 3 + 2] - coord[c * 3 + 2];
        s_xij[tid][0] = x0; s_xij[tid][1] = x1; s_xij[tid][2] = x2;
        s_d[tid] = sqrtf(x0 * x0 + x1 * x1 + x2 * x2 + 1e-8f);
    }
    __syncthreads();

    const f32x4 zf = {0.f, 0.f, 0.f, 0.f};
    const float delta = 5.0f / 31.0f;
    const float coeff = -0.5f / (delta * delta);
    const int brow = s_row[be], bcol = s_col[be], bes = s_es[be];

    float pE[8];
    short8 rB0, rB1, rB2, cB0, cB1, cB2;
    auto issue = [&](int ks) {
        if (ks < 4) {
            int kk = ks * 32 + bq;
            const short* vr = vecb1 + (size_t)brow * 384 + kk;    // vec1 bf16
            const short* vc = bun + (size_t)bcol * 1024 + kk;     // vec2 bf16
            rB0 = *(const short8*)(vr);
            rB1 = *(const short8*)(vr + 128);
            rB2 = *(const short8*)(vr + 256);
            cB0 = *(const short8*)(vc);
            cB1 = *(const short8*)(vc + 128);
            cB2 = *(const short8*)(vc + 256);
        } else if (ks == 5) {
            if (bq < 16) VLOAD8(pE, eattr + (size_t)bes * 16 + bq);
        }
    };
    auto commit = [&](int ks, int buf) {
        short (*cab)[40] = (short(*)[40])(&smem[(size_t)buf * 5120]);
        float tmp[8];
        if (ks < 4) {
#pragma unroll
            for (int j = 0; j < 8; ++j)
                tmp[j] = bf2f(rB0[j]) * bf2f(cB0[j])
                       + bf2f(rB1[j]) * bf2f(cB1[j])
                       + bf2f(rB2[j]) * bf2f(cB2[j]);
        } else if (ks == 4) {
            float dd = s_d[be];
#pragma unroll
            for (int j = 0; j < 8; ++j) {
                float x = dd - (float)(bq + j) * delta;
                tmp[j] = __expf(coeff * x * x);
            }
        } else {
#pragma unroll
            for (int j = 0; j < 8; ++j) tmp[j] = (bq < 16) ? pE[j] : 0.f;
        }
        *(short8*)&cab[be][bq] = tobf8(tmp);
    };

    // ---------------- GEMM1: [64e x 192] @ W1cde (dbuf staging) ----------
    f32x4 acc[4][2];
#pragma unroll
    for (int mt = 0; mt < 4; ++mt) { acc[mt][0] = zf; acc[mt][1] = zf; }

    issue(0); commit(0, 0);
    __syncthreads();
    for (int ks = 0; ks < 6; ++ks) {
        if (ks < 5) issue(ks + 1);
        const short (*rab)[40] = (const short(*)[40])(&smem[(size_t)(ks & 1) * 5120]);
        short8 ah4[4];
#pragma unroll
        for (int mt = 0; mt < 4; ++mt)
            ah4[mt] = *(const short8*)&rab[mt * 16 + m][kg * 8];
#pragma unroll
        for (int tt = 0; tt < 2; ++tt) {
            size_t wo = (size_t)(nb + tt * 16 + m) * 192 + ks * 32 + kg * 8;
            short8 bh = *(const short8*)(wt + O_W1H + wo);
            short8 bl = *(const short8*)(wt + O_W1L + wo);
#pragma unroll
            for (int mt = 0; mt < 4; ++mt)
                acc[mt][tt] = mfma2(ah4[mt], bh, bl, acc[mt][tt]);
        }
        if (ks < 5) commit(ks + 1, (ks + 1) & 1);
        __syncthreads();
    }
    // ab buffers dead; xh (same memory) becomes live

    // epilogue1: += hw[row] + hw[col] + b1 (bf16 bundle), silu -> xh
    {
        float b1v[2] = { b1[nb + m], b1[nb + 16 + m] };
#pragma unroll
        for (int mt = 0; mt < 4; ++mt) {
            float hb[4][4];
#pragma unroll
            for (int r = 0; r < 4; ++r) {
                int e = mt * 16 + kg * 4 + r;
                const short* hr = bun + (size_t)s_row[e] * 1024 + 768;
                const short* hc = bun + (size_t)s_col[e] * 1024 + 896;
                hb[r][0] = bf2f(hr[nb + m]);      hb[r][1] = bf2f(hc[nb + m]);
                hb[r][2] = bf2f(hr[nb + 16 + m]); hb[r][3] = bf2f(hc[nb + 16 + m]);
            }
#pragma unroll
            for (int r = 0; r < 4; ++r) {
                int e = mt * 16 + kg * 4 + r;
#pragma unroll
                for (int tt = 0; tt < 2; ++tt) {
                    int n = nb + tt * 16 + m;
                    float v = acc[mt][tt][r] + hb[r][tt * 2] + hb[r][tt * 2 + 1] + b1v[tt];
                    float sv = v * __builtin_amdgcn_rcpf(1.f + __expf(-v));
                    xh[e][n] = f2bf_rne(sv);
                }
            }
        }
    }
    __syncthreads();

    // ---------------- GEMM2: x1 @ W2t -> x2 ----------------
#pragma unroll
    for (int mt = 0; mt < 4; ++mt) { acc[mt][0] = zf; acc[mt][1] = zf; }
    for (int ks = 0; ks < 4; ++ks) {
        short8 ah4[4];
#pragma unroll
        for (int mt = 0; mt < 4; ++mt)
            ah4[mt] = *(const short8*)&xh[mt * 16 + m][ks * 32 + kg * 8];
#pragma unroll
        for (int tt = 0; tt < 2; ++tt) {
            size_t wo = (size_t)(nb + tt * 16 + m) * 128 + ks * 32 + kg * 8;
            short8 bh = *(const short8*)(wt + O_W2H + wo);
            short8 bl = *(const short8*)(wt + O_W2L + wo);
#pragma unroll
            for (int mt = 0; mt < 4; ++mt)
                acc[mt][tt] = mfma2(ah4[mt], bh, bl, acc[mt][tt]);
        }
    }
    {
        float b2v[2] = { b2[nb + m], b2[nb + 16 + m] };
#pragma unroll
        for (int mt = 0; mt < 4; ++mt)
#pragma unroll
            for (int tt = 0; tt < 2; ++tt)
#pragma unroll
                for (int r = 0; r < 4; ++r) {
                    float v = acc[mt][tt][r] + b2v[tt];
                    acc[mt][tt][r] = v * __builtin_amdgcn_rcpf(1.f + __expf(-v));
                }
    }
    __syncthreads();
#pragma unroll
    for (int mt = 0; mt < 4; ++mt)
#pragma unroll
        for (int tt = 0; tt < 2; ++tt)
#pragma unroll
            for (int r = 0; r < 4; ++r) {
                int e = mt * 16 + kg * 4 + r;
                int n = nb + tt * 16 + m;
                xh[e][n] = f2bf_rne(acc[mt][tt][r]);
            }
    __syncthreads();

    // ---------------- GEMM3: x2 @ W3t (3 col-tiles) + combined scatter ----
    float msgv[4][2][4];
    for (int c = 0; c < 3; ++c) {
        f32x4 a3[4][2];
#pragma unroll
        for (int mt = 0; mt < 4; ++mt) { a3[mt][0] = zf; a3[mt][1] = zf; }
        for (int ks = 0; ks < 4; ++ks) {
            short8 ah4[4];
#pragma unroll
            for (int mt = 0; mt < 4; ++mt)
                ah4[mt] = *(const short8*)&xh[mt * 16 + m][ks * 32 + kg * 8];
#pragma unroll
            for (int tt = 0; tt < 2; ++tt) {
                size_t wo = (size_t)(c * 128 + nb + tt * 16 + m) * 128 + ks * 32 + kg * 8;
                short8 bh = *(const short8*)(wt + O_W3H + wo);
                short8 bl = *(const short8*)(wt + O_W3L + wo);
#pragma unroll
                for (int mt = 0; mt < 4; ++mt)
                    a3[mt][tt] = mfma2(ah4[mt], bh, bl, a3[mt][tt]);
            }
        }
        float bv[2] = { b3[c * 128 + nb + m], b3[c * 128 + nb + 16 + m] };
        const int n0 = nb + m, n1 = nb + 16 + m;
        if (c == 0) {          // msg_h -> h_aggr[row], run-combined
            int cur = s_row[kg * 4];
            float s0 = 0.f, s1 = 0.f;
#pragma unroll
            for (int mt = 0; mt < 4; ++mt)
#pragma unroll
                for (int r = 0; r < 4; ++r) {
                    int rr = s_row[mt * 16 + kg * 4 + r];
                    float v0 = a3[mt][0][r] + bv[0];
                    float v1 = a3[mt][1][r] + bv[1];
                    if (rr != cur) {
                        atomicAdd(&hagg[(size_t)cur * 128 + n0], s0);
                        atomicAdd(&hagg[(size_t)cur * 128 + n1], s1);
                        cur = rr; s0 = 0.f; s1 = 0.f;
                    }
                    s0 += v0; s1 += v1;
                }
            atomicAdd(&hagg[(size_t)cur * 128 + n0], s0);
            atomicAdd(&hagg[(size_t)cur * 128 + n1], s1);
        } else if (c == 1) {
#pragma unroll
            for (int mt = 0; mt < 4; ++mt)
#pragma unroll
                for (int tt = 0; tt < 2; ++tt)
#pragma unroll
                    for (int r = 0; r < 4; ++r)
                        msgv[mt][tt][r] = a3[mt][tt][r] + bv[tt];
        } else {               // msg_x: dvec[row] += vec3[col]*msg_v + x_ij*msg_x
            int cur = s_row[kg * 4];
            float sd[6] = {0.f, 0.f, 0.f, 0.f, 0.f, 0.f};
#pragma unroll
            for (int mt = 0; mt < 4; ++mt) {
                float v3b[4][6];   // pass 1: batch scattered bf16 loads
#pragma unroll
                for (int r = 0; r < 4; ++r) {
                    int e = mt * 16 + kg * 4 + r;
                    const short* v3 = bun + (size_t)s_col[e] * 1024 + 384;
                    v3b[r][0] = bf2f(v3[n0]); v3b[r][1] = bf2f(v3[128 + n0]); v3b[r][2] = bf2f(v3[256 + n0]);
                    v3b[r][3] = bf2f(v3[n1]); v3b[r][4] = bf2f(v3[128 + n1]); v3b[r][5] = bf2f(v3[256 + n1]);
                }
#pragma unroll
                for (int r = 0; r < 4; ++r) {
                    int e = mt * 16 + kg * 4 + r;
                    int rr = s_row[e];
                    if (rr != cur) {
                        float* dst = dvec + (size_t)cur * 384;
                        atomicAdd(dst + n0,       sd[0]);
                        atomicAdd(dst + 128 + n0, sd[1]);
                        atomicAdd(dst + 256 + n0, sd[2]);
                        atomicAdd(dst + n1,       sd[3]);
                        atomicAdd(dst + 128 + n1, sd[4]);
                        atomicAdd(dst + 256 + n1, sd[5]);
                        cur = rr;
#pragma unroll
                        for (int q = 0; q < 6; ++q) sd[q] = 0.f;
                    }
                    const float xj0 = s_xij[e][0], xj1 = s_xij[e][1], xj2 = s_xij[e][2];
                    float mx0 = a3[mt][0][r] + bv[0], mx1 = a3[mt][1][r] + bv[1];
                    float mv0 = msgv[mt][0][r],       mv1 = msgv[mt][1][r];
                    sd[0] += v3b[r][0] * mv0 + xj0 * mx0;
                    sd[1] += v3b[r][1] * mv0 + xj1 * mx0;
                    sd[2] += v3b[r][2] * mv0 + xj2 * mx0;
                    sd[3] += v3b[r][3] * mv1 + xj0 * mx1;
                    sd[4] += v3b[r][4] * mv1 + xj1 * mx1;
                    sd[5] += v3b[r][5] * mv1 + xj2 * mx1;
                }
            }
            float* dst = dvec + (size_t)cur * 384;
            atomicAdd(dst + n0,       sd[0]);
            atomicAdd(dst + 128 + n0, sd[1]);
            atomicAdd(dst + 256 + n0, sd[2]);
            atomicAdd(dst + n1,       sd[3]);
            atomicAdd(dst + 128 + n1, sd[4]);
            atomicAdd(dst + 256 + n1, sd[5]);
        }
    }
}

// ---------------------------------------------------------------------------
extern "C" void kernel_launch(void* const* d_in, const int* in_sizes, int n_in,
                              void* d_out, int out_size, void* d_ws, size_t ws_size,
                              hipStream_t stream)
{
    const float* h     = (const float*)d_in[0];
    const float* vec   = (const float*)d_in[1];
    const float* coord = (const float*)d_in[2];
    const int*   eidx  = (const int*)  d_in[3];
    const float* eattr = (const float*)d_in[4];
    const float* Wvp   = (const float*)d_in[5];
    const float* W1    = (const float*)d_in[6];
    const float* b1    = (const float*)d_in[7];
    const float* W2    = (const float*)d_in[8];
    const float* b2    = (const float*)d_in[9];
    const float* W3    = (const float*)d_in[10];
    const float* b3    = (const float*)d_in[11];
    const float* Wop   = (const float*)d_in[12];
    const float* bop   = (const float*)d_in[13];

    if (ws_size < WS_FLOATS * sizeof(float)) return;

    float* ws    = (float*)d_ws;
    short* vecb1 = (short*)(ws + OFF_VECB1);
    short* bun   = (short*)(ws + OFF_BUN);
    float* hagg  = ws + OFF_HAGG;
    short* wt    = (short*)(ws + OFF_WT);
    int*   perm  = (int*)(ws + OFF_PERM);
    int*   deg   = (int*)(ws + OFF_DEG);
    int*   cur   = (int*)(ws + OFF_CUR);
    float* dh    = (float*)d_out;
    float* dvec  = (float*)d_out + (size_t)NN * HID;

    dim3 b256(256);
    hipMemsetAsync(deg, 0, NN * sizeof(int), stream);
    misc_kernel<<<25000, b256, 0, stream>>>(W1, W2, W3, Wvp, Wop, wt, eidx, deg, hagg, dvec);
    sort_scan<<<1, 1024, 0, stream>>>(deg, cur);
    sort_scatter<<<1563, b256, 0, stream>>>(eidx, cur, perm);
    // vecb1 (bf16 vec1) + bundle vec2/vec3 (bf16)
    gemm_vp<<<4688, b256, 0, stream>>>(vec, 150000, wt + O_VPH, wt + O_VPL, vecb1, bun);
    // bundle hw_row/hw_col (bf16)
    gemm_hw<<<1563, b256, 0, stream>>>(h, 50000, wt + O_HWH, wt + O_HWL, bun);
    // fused per-edge MLP + combined scatter (sorted order, 64 edges/block)
    edge_kernel<<<6250, b256, 0, stream>>>(vecb1, bun, coord, eidx, eattr, wt, perm,
                                           b1, b2, b3, hagg, dvec);
    // fused o-GEMM + finalize
    gemm_fin<<<1563, b256, 0, stream>>>(hagg, vecb1, bun, wt + O_OPH, wt + O_OPL,
                                        bop, dh, dvec, 50000);
}